// Round 1
// baseline (181.917 us; speedup 1.0000x reference)
//
#include <hip/hip_runtime.h>

#define IMG_H 8192
#define IMG_W 8192

// Each thread computes 4 contiguous output pixels in one row.
// out[y][x] = sum_{i,j in 0..2} img_pad[y+i][x+j] * w[i][j]   (cross-correlation, zero pad=1)
__global__ __launch_bounds__(256) void conv3x3_kernel(const float* __restrict__ img,
                                                      const float* __restrict__ ker,
                                                      float* __restrict__ out) {
    const int tid = blockIdx.x * 256 + threadIdx.x;
    const int xq  = tid & (IMG_W / 4 - 1);   // 2048 quads per row
    const int y   = tid >> 11;               // tid / 2048
    const int x0  = xq << 2;

    // 3x3 weights — uniform address, compiler emits scalar loads.
    const float w00 = ker[0], w01 = ker[1], w02 = ker[2];
    const float w10 = ker[3], w11 = ker[4], w12 = ker[5];
    const float w20 = ker[6], w21 = ker[7], w22 = ker[8];

    float a0 = 0.f, a1 = 0.f, a2 = 0.f, a3 = 0.f;

    const bool interior = (y >= 1) & (y <= IMG_H - 2) & (x0 >= 4) & (x0 <= IMG_W - 8);
    if (interior) {
        #pragma unroll
        for (int i = 0; i < 3; ++i) {
            const float* row = img + (size_t)(y - 1 + i) * IMG_W + x0;
            const float4 a  = *(const float4*)row;
            const float left  = row[-1];
            const float right = row[4];
            const float wa = (i == 0) ? w00 : (i == 1) ? w10 : w20;
            const float wb = (i == 0) ? w01 : (i == 1) ? w11 : w21;
            const float wc = (i == 0) ? w02 : (i == 1) ? w12 : w22;
            a0 += wa * left + wb * a.x  + wc * a.y;
            a1 += wa * a.x  + wb * a.y  + wc * a.z;
            a2 += wa * a.y  + wb * a.z  + wc * a.w;
            a3 += wa * a.z  + wb * a.w  + wc * right;
        }
    } else {
        float acc[4] = {0.f, 0.f, 0.f, 0.f};
        #pragma unroll
        for (int j = 0; j < 4; ++j) {
            const int x = x0 + j;
            float s = 0.f;
            #pragma unroll
            for (int di = -1; di <= 1; ++di) {
                const int yy = y + di;
                if (yy < 0 || yy >= IMG_H) continue;
                #pragma unroll
                for (int dj = -1; dj <= 1; ++dj) {
                    const int xx = x + dj;
                    if (xx < 0 || xx >= IMG_W) continue;
                    s += ker[(di + 1) * 3 + (dj + 1)] * img[(size_t)yy * IMG_W + xx];
                }
            }
            acc[j] = s;
        }
        a0 = acc[0]; a1 = acc[1]; a2 = acc[2]; a3 = acc[3];
    }

    *(float4*)(out + (size_t)y * IMG_W + x0) = make_float4(a0, a1, a2, a3);
}

extern "C" void kernel_launch(void* const* d_in, const int* in_sizes, int n_in,
                              void* d_out, int out_size, void* d_ws, size_t ws_size,
                              hipStream_t stream) {
    const float* img = (const float*)d_in[0];
    const float* ker = (const float*)d_in[1];
    float* out = (float*)d_out;

    const int total_threads = IMG_H * (IMG_W / 4);  // 16,777,216
    const int block = 256;
    const int grid  = total_threads / block;        // 65,536
    conv3x3_kernel<<<grid, block, 0, stream>>>(img, ker, out);
}

// Round 3
// 132.375 us; speedup vs baseline: 1.3743x; 1.3743x over previous
//
#include <hip/hip_runtime.h>

#define IMG_H 8192
#define IMG_W 8192
#define QPR   (IMG_W / 4)   // 2048 quads per row
#define RG    (IMG_H / 4)   // 2048 row-groups

typedef float floatx4 __attribute__((ext_vector_type(4)));  // native vec type for nontemporal builtin

// Each thread computes a 4-wide x 4-tall output tile.
// Interior: 18 independent loads up front (6 rows x {left, float4, right}),
// then 48 FMAs, then 4 nontemporal float4 stores.
__global__ __launch_bounds__(256) void conv3x3_kernel(const float* __restrict__ img,
                                                      const float* __restrict__ ker,
                                                      float* __restrict__ out) {
    const int tid = blockIdx.x * 256 + threadIdx.x;
    const int xq  = tid & (QPR - 1);
    const int yg  = tid >> 11;           // tid / 2048
    const int x0  = xq << 2;
    const int y0  = yg << 2;

    const float w00 = ker[0], w01 = ker[1], w02 = ker[2];
    const float w10 = ker[3], w11 = ker[4], w12 = ker[5];
    const float w20 = ker[6], w21 = ker[7], w22 = ker[8];

    const bool interior = (y0 >= 1) & (y0 + 4 <= IMG_H - 1) & (x0 >= 4) & (x0 + 4 <= IMG_W - 1);
    if (interior) {
        // Hoist all 18 loads — independent, maximizes memory-level parallelism.
        float   l[6], r[6];
        floatx4 v[6];
        const float* p = img + (size_t)(y0 - 1) * IMG_W + x0;
        #pragma unroll
        for (int i = 0; i < 6; ++i) {
            v[i] = *(const floatx4*)p;
            l[i] = p[-1];
            r[i] = p[4];
            p += IMG_W;
        }
        #pragma unroll
        for (int oy = 0; oy < 4; ++oy) {
            float a0 = 0.f, a1 = 0.f, a2 = 0.f, a3 = 0.f;
            #pragma unroll
            for (int i = 0; i < 3; ++i) {
                const int ri = oy + i;
                const float wa = (i == 0) ? w00 : (i == 1) ? w10 : w20;
                const float wb = (i == 0) ? w01 : (i == 1) ? w11 : w21;
                const float wc = (i == 0) ? w02 : (i == 1) ? w12 : w22;
                a0 += wa * l[ri]  + wb * v[ri].x + wc * v[ri].y;
                a1 += wa * v[ri].x + wb * v[ri].y + wc * v[ri].z;
                a2 += wa * v[ri].y + wb * v[ri].z + wc * v[ri].w;
                a3 += wa * v[ri].z + wb * v[ri].w + wc * r[ri];
            }
            floatx4 res = {a0, a1, a2, a3};
            // Output is write-once, never re-read: bypass caches, keep L3 for the image.
            __builtin_nontemporal_store(res, (floatx4*)(out + (size_t)(y0 + oy) * IMG_W + x0));
        }
    } else {
        // Boundary tiles (edge strips only): safe scalar path with zero padding.
        #pragma unroll
        for (int oy = 0; oy < 4; ++oy) {
            const int y = y0 + oy;
            float acc[4] = {0.f, 0.f, 0.f, 0.f};
            #pragma unroll
            for (int j = 0; j < 4; ++j) {
                const int x = x0 + j;
                float s = 0.f;
                for (int di = -1; di <= 1; ++di) {
                    const int yy = y + di;
                    if (yy < 0 || yy >= IMG_H) continue;
                    for (int dj = -1; dj <= 1; ++dj) {
                        const int xx = x + dj;
                        if (xx < 0 || xx >= IMG_W) continue;
                        s += ker[(di + 1) * 3 + (dj + 1)] * img[(size_t)yy * IMG_W + xx];
                    }
                }
                acc[j] = s;
            }
            floatx4 res = {acc[0], acc[1], acc[2], acc[3]};
            *(floatx4*)(out + (size_t)y * IMG_W + x0) = res;
        }
    }
}

extern "C" void kernel_launch(void* const* d_in, const int* in_sizes, int n_in,
                              void* d_out, int out_size, void* d_ws, size_t ws_size,
                              hipStream_t stream) {
    const float* img = (const float*)d_in[0];
    const float* ker = (const float*)d_in[1];
    float* out = (float*)d_out;

    const int total_threads = QPR * RG;      // 4,194,304
    const int block = 256;
    const int grid  = total_threads / block; // 16,384
    conv3x3_kernel<<<grid, block, 0, stream>>>(img, ker, out);
}